// Round 2
// baseline (20680.527 us; speedup 1.0000x reference)
//
#include <hip/hip_runtime.h>
#include <stdint.h>

// B=1, S=2048, D=4096, H=32, HD=128.
// Inputs/outputs are fp32 (round-1 NaN proved inputs are not bf16: reading
// fp32 as bf16 halves hits inf/NaN encodings). Comparison tolerance is
// bf16-grade (0.109375), so intermediates are bf16 with fp32 accumulation.
// Workspace (96 MB):
//   [ 0M,32M)  Wt  : transposed+bf16 weight scratch (4096x4096), reused 4x
//   [32M,48M)  Xbf : hidden_state as bf16; reused as AO after attention
//   [48M,64M)  Q   [64M,80M) K   [80M,96M) V   (2048x4096 bf16 each)

#define SS 2048
#define DD 4096
#define NH 32
#define HD 128
#define NEGV -1000000000.0f

typedef __bf16 bf16x8 __attribute__((ext_vector_type(8)));
typedef float f32x4 __attribute__((ext_vector_type(4)));

__device__ __forceinline__ float bf2f(uint16_t u) {
    union { uint32_t i; float f; } v; v.i = ((uint32_t)u) << 16; return v.f;
}
__device__ __forceinline__ uint16_t f2bf(float f) {
    union { float f; uint32_t i; } v; v.f = f;
    uint32_t x = v.i;
    uint32_t r = (x + 0x7fffu + ((x >> 16) & 1u)) >> 16;
    return (uint16_t)r;
}

__device__ __forceinline__ void storeOut(float* C, size_t i, float v) { C[i] = v; }
__device__ __forceinline__ void storeOut(uint16_t* C, size_t i, float v) { C[i] = f2bf(v); }

// X fp32 -> bf16, 8 elems/thread. n must be multiple of 2048*blocks.
__global__ void xconv_kernel(const float* __restrict__ in, uint16_t* __restrict__ out) {
    int i = blockIdx.x * blockDim.x + threadIdx.x;
    const float4* in4 = (const float4*)in;
    float4 a = in4[2 * i], b = in4[2 * i + 1];
    uint4 o;
    o.x = (uint32_t)f2bf(a.x) | ((uint32_t)f2bf(a.y) << 16);
    o.y = (uint32_t)f2bf(a.z) | ((uint32_t)f2bf(a.w) << 16);
    o.z = (uint32_t)f2bf(b.x) | ((uint32_t)f2bf(b.y) << 16);
    o.w = (uint32_t)f2bf(b.z) | ((uint32_t)f2bf(b.w) << 16);
    ((uint4*)out)[i] = o;
}

// out[n][k] = bf16(in[k][n]), 4096x4096. grid(128,128), block(32,8)
__global__ void wtrans_kernel(const float* __restrict__ in,
                              uint16_t* __restrict__ out) {
    __shared__ uint16_t tile[32][33];
    int bx = blockIdx.x * 32, by = blockIdx.y * 32;
    int tx = threadIdx.x, ty = threadIdx.y;
    #pragma unroll
    for (int i = 0; i < 32; i += 8)
        tile[ty + i][tx] = f2bf(in[(size_t)(by + ty + i) * DD + bx + tx]);
    __syncthreads();
    #pragma unroll
    for (int i = 0; i < 32; i += 8)
        out[(size_t)(bx + ty + i) * DD + by + tx] = tile[tx][ty + i];
}

// C[M][N] = A[M][K] @ Bt[N][K]^T, bf16 in, OutT out, fp32 acc.
// 128x128 tile, BK=32, 4 waves of 4x4 16x16x32 MFMA. M,N,K mult of 128.
template <typename OutT>
__global__ __launch_bounds__(256) void gemm_bt(const uint16_t* __restrict__ A,
                                               const uint16_t* __restrict__ Bt,
                                               OutT* __restrict__ C,
                                               int M, int N, int K) {
    __shared__ uint16_t sA[128 * 32];
    __shared__ uint16_t sB[128 * 32];
    int t = threadIdx.x;
    int lane = t & 63, w = t >> 6;
    int wm = (w >> 1) * 64, wn = (w & 1) * 64;
    int rowBase = blockIdx.y * 128, colBase = blockIdx.x * 128;
    f32x4 acc[4][4] = {};

    int lr = lane & 15;
    int kq = (lane >> 4) * 8;

    for (int k0 = 0; k0 < K; k0 += 32) {
        __syncthreads();
        #pragma unroll
        for (int p = 0; p < 2; ++p) {
            int c = p * 256 + t;
            int r = c >> 2;
            int cc = (c & 3) * 8;
            *(uint4*)(&sA[r * 32 + cc]) =
                *(const uint4*)(&A[(size_t)(rowBase + r) * K + k0 + cc]);
            *(uint4*)(&sB[r * 32 + cc]) =
                *(const uint4*)(&Bt[(size_t)(colBase + r) * K + k0 + cc]);
        }
        __syncthreads();

        bf16x8 af[4], bfr[4];
        #pragma unroll
        for (int i = 0; i < 4; ++i) {
            af[i]  = *(const bf16x8*)(&sA[(wm + i * 16 + lr) * 32 + kq]);
            bfr[i] = *(const bf16x8*)(&sB[(wn + i * 16 + lr) * 32 + kq]);
        }
        #pragma unroll
        for (int mt = 0; mt < 4; ++mt)
            #pragma unroll
            for (int nt = 0; nt < 4; ++nt)
                acc[mt][nt] = __builtin_amdgcn_mfma_f32_16x16x32_bf16(
                    af[mt], bfr[nt], acc[mt][nt], 0, 0, 0);
    }

    int q = lane >> 4;
    #pragma unroll
    for (int mt = 0; mt < 4; ++mt)
        #pragma unroll
        for (int nt = 0; nt < 4; ++nt)
            #pragma unroll
            for (int r = 0; r < 4; ++r) {
                int row = rowBase + wm + mt * 16 + q * 4 + r;
                int col = colBase + wn + nt * 16 + lr;
                storeOut(C, (size_t)row * N + col, acc[mt][nt][r]);
            }
}

// Full-width RoPE (rotate-half at D/2=2048), in-place on bf16 Q and K.
// cos/sin are fp32 (1,S,D). One thread per (s, d<2048).
__global__ void rope_kernel(uint16_t* __restrict__ q, uint16_t* __restrict__ k,
                            const float* __restrict__ cosb,
                            const float* __restrict__ sinb) {
    int idx = blockIdx.x * blockDim.x + threadIdx.x;
    int s = idx >> 11;
    int d = idx & 2047;
    size_t i0 = (size_t)s * DD + d, i1 = i0 + 2048;
    float c0 = cosb[i0], c1 = cosb[i1];
    float s0 = sinb[i0], s1 = sinb[i1];
    float q0 = bf2f(q[i0]), q1 = bf2f(q[i1]);
    q[i0] = f2bf(q0 * c0 - q1 * s0);
    q[i1] = f2bf(q1 * c1 + q0 * s1);
    float k0 = bf2f(k[i0]), k1 = bf2f(k[i1]);
    k[i0] = f2bf(k0 * c0 - k1 * s0);
    k[i1] = f2bf(k1 * c1 + k0 * s1);
}

// One block per (query row, head). Scores -> softmax -> P@V.
// Mask per reference: tri(s,s)==1 (j<=i, incl diag) -> +NEG, plus attn_mask.
__global__ __launch_bounds__(256) void attn_kernel(const uint16_t* __restrict__ Q,
                                                   const uint16_t* __restrict__ K,
                                                   const uint16_t* __restrict__ V,
                                                   const float* __restrict__ mask,
                                                   uint16_t* __restrict__ O) {
    __shared__ float p_sh[SS];
    __shared__ float q_sh[HD];
    __shared__ float redm[4], reds[4];
    __shared__ float oacc[256];

    int sq = blockIdx.x, h = blockIdx.y;
    int t = threadIdx.x;
    int lane = t & 63, w = t >> 6;
    int base = h * HD;

    if (t < HD) q_sh[t] = bf2f(Q[(size_t)sq * DD + base + t]);
    __syncthreads();

    float sc[8];
    float smax = -3.4e38f;
    #pragma unroll
    for (int i = 0; i < 8; ++i) {
        int kk = t + i * 256;
        const uint16_t* kr = &K[(size_t)kk * DD + base];
        float dot = 0.f;
        #pragma unroll
        for (int dd = 0; dd < HD; dd += 8) {
            uint4 u = *(const uint4*)(&kr[dd]);
            uint32_t uu[4] = {u.x, u.y, u.z, u.w};
            #pragma unroll
            for (int j = 0; j < 4; ++j) {
                union { uint32_t i; float f; } lo, hi;
                lo.i = uu[j] << 16; hi.i = uu[j] & 0xffff0000u;
                dot += q_sh[dd + 2 * j] * lo.f + q_sh[dd + 2 * j + 1] * hi.f;
            }
        }
        float s = dot * 0.015625f + mask[(size_t)sq * SS + kk];
        if (kk <= sq) s += NEGV;
        sc[i] = s;
        smax = fmaxf(smax, s);
    }
    #pragma unroll
    for (int off = 32; off > 0; off >>= 1)
        smax = fmaxf(smax, __shfl_down(smax, off));
    if (lane == 0) redm[w] = smax;
    __syncthreads();
    float m = fmaxf(fmaxf(redm[0], redm[1]), fmaxf(redm[2], redm[3]));

    float lsum = 0.f;
    #pragma unroll
    for (int i = 0; i < 8; ++i) {
        float e = __expf(sc[i] - m);
        p_sh[t + i * 256] = e;
        lsum += e;
    }
    #pragma unroll
    for (int off = 32; off > 0; off >>= 1)
        lsum += __shfl_down(lsum, off);
    if (lane == 0) reds[w] = lsum;
    __syncthreads();
    float inv = 1.f / (reds[0] + reds[1] + reds[2] + reds[3]);

    int dd = t & 127, half = t >> 7;
    float acc = 0.f;
    int kk0 = half * 1024;
    for (int kk = kk0; kk < kk0 + 1024; ++kk)
        acc += p_sh[kk] * bf2f(V[(size_t)kk * DD + base + dd]);
    oacc[t] = acc;
    __syncthreads();
    if (t < 128) {
        float o = (oacc[t] + oacc[t + 128]) * inv;
        O[(size_t)sq * DD + base + t] = f2bf(o);
    }
}

extern "C" void kernel_launch(void* const* d_in, const int* in_sizes, int n_in,
                              void* d_out, int out_size, void* d_ws, size_t ws_size,
                              hipStream_t stream) {
    const float* X    = (const float*)d_in[0];
    const float* mask = (const float*)d_in[1];
    const float* cosb = (const float*)d_in[2];
    const float* sinb = (const float*)d_in[3];
    const float* wq   = (const float*)d_in[4];
    const float* wk   = (const float*)d_in[5];
    const float* wv   = (const float*)d_in[6];
    const float* wo   = (const float*)d_in[7];
    float* out = (float*)d_out;

    char* ws = (char*)d_ws;
    uint16_t* Wt  = (uint16_t*)ws;                            // 32 MB
    uint16_t* Xbf = (uint16_t*)(ws + (size_t)33554432);       // 16 MB
    uint16_t* Q   = Xbf + (size_t)SS * DD;
    uint16_t* Kb  = Q  + (size_t)SS * DD;
    uint16_t* Vb  = Kb + (size_t)SS * DD;
    uint16_t* AO  = Xbf;  // X dead after V gemm; reuse for attention output

    dim3 tgrid(DD / 32, DD / 32), tblock(32, 8);
    dim3 ggrid(DD / 128, SS / 128), gblock(256);

    xconv_kernel<<<(SS * DD) / (256 * 8), 256, 0, stream>>>(X, Xbf);

    wtrans_kernel<<<tgrid, tblock, 0, stream>>>(wq, Wt);
    gemm_bt<<<ggrid, gblock, 0, stream>>>(Xbf, Wt, Q, SS, DD, DD);
    wtrans_kernel<<<tgrid, tblock, 0, stream>>>(wk, Wt);
    gemm_bt<<<ggrid, gblock, 0, stream>>>(Xbf, Wt, Kb, SS, DD, DD);
    wtrans_kernel<<<tgrid, tblock, 0, stream>>>(wv, Wt);
    gemm_bt<<<ggrid, gblock, 0, stream>>>(Xbf, Wt, Vb, SS, DD, DD);

    rope_kernel<<<(SS * 2048) / 256, 256, 0, stream>>>(Q, Kb, cosb, sinb);

    attn_kernel<<<dim3(SS, NH), 256, 0, stream>>>(Q, Kb, Vb, mask, AO);

    wtrans_kernel<<<tgrid, tblock, 0, stream>>>(wo, Wt);
    gemm_bt<<<ggrid, gblock, 0, stream>>>(AO, Wt, out, SS, DD, DD);
}

// Round 3
// 1186.468 us; speedup vs baseline: 17.4303x; 17.4303x over previous
//
#include <hip/hip_runtime.h>
#include <stdint.h>

// B=1, S=2048, D=4096, H=32, HD=128. fp32 inputs/outputs, bf16 intermediates.
// Round 3: MFMA flash attention (Q@K^T -> online softmax -> O^T = VT @ P^T),
// V kept transposed (VT[d][s]) by swapping GEMM operands so all hot-loop LDS
// reads are contiguous ds_read_b128.
// Workspace (96 MB):
//   [ 0M,32M)  Wt  : transposed+bf16 weight scratch (4096x4096), reused 4x
//   [32M,48M)  Xbf : hidden_state bf16; reused as AO after attention
//   [48M,64M)  Q   [64M,80M) K  (2048x4096)   [80M,96M) VT (4096x2048)

#define SS 2048
#define DD 4096
#define NH 32
#define HD 128
#define NEGV -1000000000.0f
#define LDP 136  // LDS row stride (128 + 8 pad): 272B = 17*16B, 16B-aligned rows

typedef __bf16 bf16x8 __attribute__((ext_vector_type(8)));
typedef float f32x4 __attribute__((ext_vector_type(4)));

__device__ __forceinline__ float bf2f(uint16_t u) {
    union { uint32_t i; float f; } v; v.i = ((uint32_t)u) << 16; return v.f;
}
__device__ __forceinline__ uint16_t f2bf(float f) {
    union { float f; uint32_t i; } v; v.f = f;
    uint32_t x = v.i;
    uint32_t r = (x + 0x7fffu + ((x >> 16) & 1u)) >> 16;
    return (uint16_t)r;
}

__device__ __forceinline__ void storeOut(float* C, size_t i, float v) { C[i] = v; }
__device__ __forceinline__ void storeOut(uint16_t* C, size_t i, float v) { C[i] = f2bf(v); }

__global__ void xconv_kernel(const float* __restrict__ in, uint16_t* __restrict__ out) {
    int i = blockIdx.x * blockDim.x + threadIdx.x;
    const float4* in4 = (const float4*)in;
    float4 a = in4[2 * i], b = in4[2 * i + 1];
    uint4 o;
    o.x = (uint32_t)f2bf(a.x) | ((uint32_t)f2bf(a.y) << 16);
    o.y = (uint32_t)f2bf(a.z) | ((uint32_t)f2bf(a.w) << 16);
    o.z = (uint32_t)f2bf(b.x) | ((uint32_t)f2bf(b.y) << 16);
    o.w = (uint32_t)f2bf(b.z) | ((uint32_t)f2bf(b.w) << 16);
    ((uint4*)out)[i] = o;
}

// out[n][k] = bf16(in[k][n]), 4096x4096
__global__ void wtrans_kernel(const float* __restrict__ in,
                              uint16_t* __restrict__ out) {
    __shared__ uint16_t tile[32][33];
    int bx = blockIdx.x * 32, by = blockIdx.y * 32;
    int tx = threadIdx.x, ty = threadIdx.y;
    #pragma unroll
    for (int i = 0; i < 32; i += 8)
        tile[ty + i][tx] = f2bf(in[(size_t)(by + ty + i) * DD + bx + tx]);
    __syncthreads();
    #pragma unroll
    for (int i = 0; i < 32; i += 8)
        out[(size_t)(bx + ty + i) * DD + by + tx] = tile[tx][ty + i];
}

// C[M][N] = A[M][K] @ Bt[N][K]^T (bf16 in, fp32 acc). M,N,K multiples of 128.
template <typename OutT>
__global__ __launch_bounds__(256) void gemm_bt(const uint16_t* __restrict__ A,
                                               const uint16_t* __restrict__ Bt,
                                               OutT* __restrict__ C,
                                               int M, int N, int K) {
    __shared__ uint16_t sA[128 * 32];
    __shared__ uint16_t sB[128 * 32];
    int t = threadIdx.x;
    int lane = t & 63, w = t >> 6;
    int wm = (w >> 1) * 64, wn = (w & 1) * 64;
    int rowBase = blockIdx.y * 128, colBase = blockIdx.x * 128;
    f32x4 acc[4][4] = {};

    int lr = lane & 15;
    int kq = (lane >> 4) * 8;

    for (int k0 = 0; k0 < K; k0 += 32) {
        __syncthreads();
        #pragma unroll
        for (int p = 0; p < 2; ++p) {
            int c = p * 256 + t;
            int r = c >> 2;
            int cc = (c & 3) * 8;
            *(uint4*)(&sA[r * 32 + cc]) =
                *(const uint4*)(&A[(size_t)(rowBase + r) * K + k0 + cc]);
            *(uint4*)(&sB[r * 32 + cc]) =
                *(const uint4*)(&Bt[(size_t)(colBase + r) * K + k0 + cc]);
        }
        __syncthreads();

        bf16x8 af[4], bfr[4];
        #pragma unroll
        for (int i = 0; i < 4; ++i) {
            af[i]  = *(const bf16x8*)(&sA[(wm + i * 16 + lr) * 32 + kq]);
            bfr[i] = *(const bf16x8*)(&sB[(wn + i * 16 + lr) * 32 + kq]);
        }
        #pragma unroll
        for (int mt = 0; mt < 4; ++mt)
            #pragma unroll
            for (int nt = 0; nt < 4; ++nt)
                acc[mt][nt] = __builtin_amdgcn_mfma_f32_16x16x32_bf16(
                    af[mt], bfr[nt], acc[mt][nt], 0, 0, 0);
    }

    int q = lane >> 4;
    #pragma unroll
    for (int mt = 0; mt < 4; ++mt)
        #pragma unroll
        for (int nt = 0; nt < 4; ++nt)
            #pragma unroll
            for (int r = 0; r < 4; ++r) {
                int row = rowBase + wm + mt * 16 + q * 4 + r;
                int col = colBase + wn + nt * 16 + lr;
                storeOut(C, (size_t)row * N + col, acc[mt][nt][r]);
            }
}

// RoPE in-place on bf16 Q and K; cos/sin fp32 (1,S,D); rotate-half at 2048.
__global__ void rope_kernel(uint16_t* __restrict__ q, uint16_t* __restrict__ k,
                            const float* __restrict__ cosb,
                            const float* __restrict__ sinb) {
    int idx = blockIdx.x * blockDim.x + threadIdx.x;
    int s = idx >> 11;
    int d = idx & 2047;
    size_t i0 = (size_t)s * DD + d, i1 = i0 + 2048;
    float c0 = cosb[i0], c1 = cosb[i1];
    float s0 = sinb[i0], s1 = sinb[i1];
    float q0 = bf2f(q[i0]), q1 = bf2f(q[i1]);
    q[i0] = f2bf(q0 * c0 - q1 * s0);
    q[i1] = f2bf(q1 * c1 + q0 * s1);
    float k0 = bf2f(k[i0]), k1 = bf2f(k[i1]);
    k[i0] = f2bf(k0 * c0 - k1 * s0);
    k[i1] = f2bf(k1 * c1 + k0 * s1);
}

// Flash attention: block = (head, 64 q-rows), 4 waves. K-tiles of 128.
// S = Q@K^T (C-layout: col=kk=lane&15, row=quad*4+reg), online softmax,
// P->LDS bf16, O^T = VT_tile @ P^T accumulated in registers across tiles.
__global__ __launch_bounds__(256) void fattn_kernel(
    const uint16_t* __restrict__ Q, const uint16_t* __restrict__ K,
    const uint16_t* __restrict__ VT, const float* __restrict__ mask,
    uint16_t* __restrict__ O)
{
    __shared__ uint16_t sQ[64 * LDP];
    __shared__ uint16_t sK[128 * LDP];   // reused as sO[m][dd] in epilogue
    __shared__ uint16_t sVt[128 * LDP];
    __shared__ uint16_t sP[64 * LDP];
    __shared__ float sAlpha[64];
    __shared__ float sL[64];

    int h = blockIdx.y, q0 = blockIdx.x * 64;
    int base = h * HD;
    int t = threadIdx.x;
    int lane = t & 63, w = t >> 6;
    int lr = lane & 15, quad = lane >> 4;
    int mw = w * 16;

    for (int c = t; c < 64 * 16; c += 256) {
        int m = c >> 4, dc = (c & 15) * 8;
        *(uint4*)(&sQ[m * LDP + dc]) =
            *(const uint4*)(&Q[(size_t)(q0 + m) * DD + base + dc]);
    }

    f32x4 oacc[2][4] = {};   // [dt][nt] : rows dd=(2w+dt)*16+quad*4+reg, cols m=nt*16+lr
    float m_pr[4], l_run[4];
    #pragma unroll
    for (int r = 0; r < 4; ++r) { m_pr[r] = -3.0e38f; l_run[r] = 0.f; }

    for (int kt = 0; kt < SS / 128; ++kt) {
        __syncthreads();
        for (int c = t; c < 128 * 16; c += 256) {
            int r = c >> 4, dc = (c & 15) * 8;
            *(uint4*)(&sK[r * LDP + dc]) =
                *(const uint4*)(&K[(size_t)(kt * 128 + r) * DD + base + dc]);
            *(uint4*)(&sVt[r * LDP + dc]) =
                *(const uint4*)(&VT[(size_t)(base + r) * SS + kt * 128 + dc]);
        }
        __syncthreads();

        // QK^T: this wave owns q-rows mw..mw+15, all 128 kk
        f32x4 sacc[8] = {};
        #pragma unroll
        for (int kc = 0; kc < 4; ++kc) {
            bf16x8 af = *(const bf16x8*)(&sQ[(mw + lr) * LDP + kc * 32 + quad * 8]);
            #pragma unroll
            for (int nt = 0; nt < 8; ++nt) {
                bf16x8 bfr = *(const bf16x8*)(&sK[(nt * 16 + lr) * LDP + kc * 32 + quad * 8]);
                sacc[nt] = __builtin_amdgcn_mfma_f32_16x16x32_bf16(af, bfr, sacc[nt], 0, 0, 0);
            }
        }

        // scores: scale + attn_mask + anti-causal tri (kk <= qrow -> +NEG)
        float sc[8][4];
        #pragma unroll
        for (int nt = 0; nt < 8; ++nt) {
            int kk = kt * 128 + nt * 16 + lr;
            #pragma unroll
            for (int r = 0; r < 4; ++r) {
                int qrow = q0 + mw + quad * 4 + r;
                float s = sacc[nt][r] * 0.015625f + mask[(size_t)qrow * SS + kk];
                if (kk <= qrow) s += NEGV;
                sc[nt][r] = s;
            }
        }

        float mnew[4], alpha[4];
        #pragma unroll
        for (int r = 0; r < 4; ++r) {
            float mx = sc[0][r];
            #pragma unroll
            for (int nt = 1; nt < 8; ++nt) mx = fmaxf(mx, sc[nt][r]);
            #pragma unroll
            for (int off = 1; off < 16; off <<= 1)
                mx = fmaxf(mx, __shfl_xor(mx, off));
            mnew[r] = fmaxf(m_pr[r], mx);
            alpha[r] = __expf(m_pr[r] - mnew[r]);
            m_pr[r] = mnew[r];
        }

        float ps[4] = {0.f, 0.f, 0.f, 0.f};
        #pragma unroll
        for (int nt = 0; nt < 8; ++nt) {
            #pragma unroll
            for (int r = 0; r < 4; ++r) {
                float p = __expf(sc[nt][r] - mnew[r]);
                ps[r] += p;
                sP[(mw + quad * 4 + r) * LDP + nt * 16 + lr] = f2bf(p);
            }
        }
        #pragma unroll
        for (int r = 0; r < 4; ++r) {
            #pragma unroll
            for (int off = 1; off < 16; off <<= 1)
                ps[r] += __shfl_xor(ps[r], off);
            l_run[r] = l_run[r] * alpha[r] + ps[r];
            if (lr == 0) sAlpha[mw + quad * 4 + r] = alpha[r];
        }
        __syncthreads();

        // O^T += VT_tile @ P^T ; wave owns dd-tiles 2w, 2w+1
        float a_col[4];
        #pragma unroll
        for (int nt = 0; nt < 4; ++nt) a_col[nt] = sAlpha[nt * 16 + lr];
        #pragma unroll
        for (int dt = 0; dt < 2; ++dt)
            #pragma unroll
            for (int nt = 0; nt < 4; ++nt)
                #pragma unroll
                for (int r = 0; r < 4; ++r)
                    oacc[dt][nt][r] *= a_col[nt];
        #pragma unroll
        for (int kc = 0; kc < 4; ++kc) {
            bf16x8 bfr[4];
            #pragma unroll
            for (int nt = 0; nt < 4; ++nt)
                bfr[nt] = *(const bf16x8*)(&sP[(nt * 16 + lr) * LDP + kc * 32 + quad * 8]);
            #pragma unroll
            for (int dt = 0; dt < 2; ++dt) {
                bf16x8 af = *(const bf16x8*)(&sVt[((2 * w + dt) * 16 + lr) * LDP + kc * 32 + quad * 8]);
                #pragma unroll
                for (int nt = 0; nt < 4; ++nt)
                    oacc[dt][nt] = __builtin_amdgcn_mfma_f32_16x16x32_bf16(af, bfr[nt], oacc[dt][nt], 0, 0, 0);
            }
        }
    }

    #pragma unroll
    for (int r = 0; r < 4; ++r)
        if (lr == 0) sL[mw + quad * 4 + r] = l_run[r];
    __syncthreads();

    // O^T regs -> sO (=sK) [m][dd] with 1/l scaling, then coalesced store
    float linv[4];
    #pragma unroll
    for (int nt = 0; nt < 4; ++nt) linv[nt] = 1.f / sL[nt * 16 + lr];
    #pragma unroll
    for (int dt = 0; dt < 2; ++dt) {
        int ddl = (2 * w + dt) * 16 + quad * 4;
        #pragma unroll
        for (int nt = 0; nt < 4; ++nt) {
            int ml = nt * 16 + lr;
            #pragma unroll
            for (int r = 0; r < 4; ++r)
                sK[ml * LDP + ddl + r] = f2bf(oacc[dt][nt][r] * linv[nt]);
        }
    }
    __syncthreads();
    for (int c = t; c < 64 * 16; c += 256) {
        int m = c >> 4, dc = (c & 15) * 8;
        *(uint4*)(&O[(size_t)(q0 + m) * DD + base + dc]) =
            *(const uint4*)(&sK[m * LDP + dc]);
    }
}

extern "C" void kernel_launch(void* const* d_in, const int* in_sizes, int n_in,
                              void* d_out, int out_size, void* d_ws, size_t ws_size,
                              hipStream_t stream) {
    const float* X    = (const float*)d_in[0];
    const float* mask = (const float*)d_in[1];
    const float* cosb = (const float*)d_in[2];
    const float* sinb = (const float*)d_in[3];
    const float* wq   = (const float*)d_in[4];
    const float* wk   = (const float*)d_in[5];
    const float* wv   = (const float*)d_in[6];
    const float* wo   = (const float*)d_in[7];
    float* out = (float*)d_out;

    char* ws = (char*)d_ws;
    uint16_t* Wt  = (uint16_t*)ws;                            // 32 MB
    uint16_t* Xbf = (uint16_t*)(ws + (size_t)33554432);       // 16 MB
    uint16_t* Q   = Xbf + (size_t)SS * DD;
    uint16_t* Kb  = Q  + (size_t)SS * DD;
    uint16_t* VT  = Kb + (size_t)SS * DD;                     // [D][S]
    uint16_t* AO  = Xbf;  // X dead after VT gemm; reuse for attention output

    dim3 tgrid(DD / 32, DD / 32), tblock(32, 8);
    dim3 ggrid(DD / 128, SS / 128), gblock(256);

    xconv_kernel<<<(SS * DD) / (256 * 8), 256, 0, stream>>>(X, Xbf);

    wtrans_kernel<<<tgrid, tblock, 0, stream>>>(wq, Wt);
    gemm_bt<<<ggrid, gblock, 0, stream>>>(Xbf, Wt, Q, SS, DD, DD);
    wtrans_kernel<<<tgrid, tblock, 0, stream>>>(wk, Wt);
    gemm_bt<<<ggrid, gblock, 0, stream>>>(Xbf, Wt, Kb, SS, DD, DD);
    wtrans_kernel<<<tgrid, tblock, 0, stream>>>(wv, Wt);
    // VT[d][s] = sum_k Wv[k][d] * X[s][k]  (A = Wv^T rows, Bt = X rows)
    gemm_bt<<<dim3(SS / 128, DD / 128), gblock, 0, stream>>>(Wt, Xbf, VT, DD, SS, DD);

    rope_kernel<<<(SS * 2048) / 256, 256, 0, stream>>>(Q, Kb, cosb, sinb);

    fattn_kernel<<<dim3(SS / 64, NH), 256, 0, stream>>>(Q, Kb, VT, mask, AO);

    wtrans_kernel<<<tgrid, tblock, 0, stream>>>(wo, Wt);
    gemm_bt<<<ggrid, gblock, 0, stream>>>(AO, Wt, out, SS, DD, DD);
}